// Round 5
// baseline (103.708 us; speedup 1.0000x reference)
//
#include <hip/hip_runtime.h>
#include <hip/hip_bf16.h>

#define EPS 1e-5f

typedef unsigned short u16;
typedef __attribute__((ext_vector_type(8))) __bf16 bf16x8;
typedef __attribute__((ext_vector_type(4))) float f32x4;
typedef __attribute__((ext_vector_type(4))) unsigned short u16x4;

// round-to-nearest-even f32 -> bf16
__device__ __forceinline__ u16 f2bf(float f) {
  unsigned int u = __float_as_uint(f);
  u += 0x7fffu + ((u >> 16) & 1u);
  return (u16)(u >> 16);
}

// ---------------------------------------------------------------------------
// prep kernel (one launch, 328 independent blocks):
//   blocks   0..255 -> L/R projections (layer-0 fold), 8 objects each
//   blocks 256..287 -> fold BN into G layers 1,2, FRAGMENT-MAJOR bf16:
//       Wf[l][kk][cb][lane=g*16+r][e] = W_folded[u=cb*16+r][k=kk*32+g*8+e]
//       (rn_main fragment load = base + frag*1KB + lane*16B, coalesced)
//   blocks 288..319 -> fold BN into F layers 0,1, COLUMN-MAJOR f32:
//       fWt[l][k][u] = fW[l][u][k] * s[u];  fbias[l][u] folded
//       (head's matvec load is coalesced across lanes=u)
//   blocks 320..327 -> transpose final layer: foWt[k][u] = foW[u][k]
// ---------------------------------------------------------------------------
__global__ __launch_bounds__(256) void prep(
    const float* __restrict__ x, const float* __restrict__ gW,
    const float* __restrict__ gb, const float* __restrict__ ggamma,
    const float* __restrict__ gbeta, const float* __restrict__ gmean,
    const float* __restrict__ gvar,
    const float* __restrict__ fW, const float* __restrict__ fb,
    const float* __restrict__ fgamma, const float* __restrict__ fbeta,
    const float* __restrict__ fmean, const float* __restrict__ fvar,
    const float* __restrict__ foW,
    u16* __restrict__ Wf, float* __restrict__ biasOut,
    float* __restrict__ fWt, float* __restrict__ fbias,
    float* __restrict__ foWt,
    float* __restrict__ Lf, float* __restrict__ Rf) {
  const int t = threadIdx.x;
  const int blk = blockIdx.x;

  if (blk >= 320) {
    // ---- foW transpose: 8 blocks, 16 rows (u) each
    const int row = (blk - 320) * 16 + (t >> 4);
    const int c0 = (t & 15) * 16;
    const float* wrow = foW + (size_t)row * 256;
    #pragma unroll
    for (int c = 0; c < 16; ++c) {
      const int k = c0 + c;
      foWt[(size_t)k * 128 + row] = wrow[k];
    }
    return;
  }
  if (blk >= 288) {
    // ---- F fold: 32 blocks, 16 rows (u) of one layer each
    const int idx = blk - 288;
    const int l = idx >> 4;
    const int row = (idx & 15) * 16 + (t >> 4);
    const int c0 = (t & 15) * 16;
    const int fi = l * 256 + row;
    const float s = fgamma[fi] * rsqrtf(fvar[fi] + EPS);
    if (c0 == 0) fbias[l * 256 + row] = (fb[fi] - fmean[fi]) * s + fbeta[fi];
    const float* wrow = fW + (size_t)fi * 256;
    #pragma unroll
    for (int c = 0; c < 16; ++c) {
      const int k = c0 + c;
      fWt[((size_t)l * 256 + k) * 256 + row] = wrow[k] * s;
    }
    return;
  }
  if (blk >= 256) {
    // ---- G fold: 32 blocks, 16 rows (u) of one layer each
    const int idx = blk - 256;
    const int l = idx >> 4;                 // 0,1 -> g layer 1,2
    const int gl = l + 1;
    const int row = (idx & 15) * 16 + (t >> 4);
    const int c0 = (t & 15) * 16;
    const int gi = gl * 256 + row;
    const float s = ggamma[gi] * rsqrtf(gvar[gi] + EPS);
    if (c0 == 0) biasOut[l * 256 + row] = (gb[gi] - gmean[gi]) * s + gbeta[gi];
    const float* wrow = gW + (size_t)gi * 256;
    const int r = row & 15;
    const int cb = row >> 4;
    #pragma unroll
    for (int c = 0; c < 16; ++c) {
      const int k = c0 + c;
      const int kk = k >> 5;
      const int g = (k >> 3) & 3;
      const int e = k & 7;
      const size_t flat =
          (((((size_t)l * 8 + kk) * 16 + cb) * 64) + g * 16 + r) * 8 + e;
      Wf[flat] = f2bf(wrow[k] * s);
    }
    return;
  }
  // ---- L/R part: 256 blocks = 32 batches x 8 chunks of 8 objects
  const int b = blk >> 3;
  const int chunk = blk & 7;
  __shared__ __align__(16) float xs[8][128];
  {
    const float4* src = (const float4*)(x + ((size_t)b * 64 + chunk * 8) * 128);
    float4* dst = (float4*)(&xs[0][0]);
    if (t < 256) dst[t] = src[t];
  }
  __syncthreads();
  const int u = t;
  float accL[8], accR[8];
  #pragma unroll
  for (int nn = 0; nn < 8; ++nn) { accL[nn] = 0.f; accR[nn] = 0.f; }
  const float4* wl = (const float4*)(gW + (size_t)u * 256);
  const float4* wr = (const float4*)(gW + (size_t)u * 256 + 128);
  for (int d4 = 0; d4 < 32; ++d4) {
    const float4 a = wl[d4];
    const float4 c = wr[d4];
    #pragma unroll
    for (int nn = 0; nn < 8; ++nn) {
      const float4 xv = *((const float4*)&xs[nn][d4 * 4]);
      accL[nn] += a.x * xv.x + a.y * xv.y + a.z * xv.z + a.w * xv.w;
      accR[nn] += c.x * xv.x + c.y * xv.y + c.z * xv.z + c.w * xv.w;
    }
  }
  const float s = ggamma[u] * rsqrtf(gvar[u] + EPS);
  const float lb = (gb[u] - gmean[u]) * s + gbeta[u];
  const int n0 = chunk * 8;
  #pragma unroll
  for (int nn = 0; nn < 8; ++nn) {
    Lf[((size_t)b * 64 + n0 + nn) * 256 + u] = accL[nn] * s + lb;
    Rf[((size_t)b * 64 + n0 + nn) * 256 + u] = accR[nn] * s;
  }
}

// ---------------------------------------------------------------------------
// Main fused kernel: per (i, b): 64 pairs (i, j=0..63)
//   h  = relu(L_i + R_j)            -> LDS bf16 (XOR-swizzled), 32 KiB
//   h' = relu(W1 h + b1)            -> same LDS buffer (regs across barrier)
//   out = relu(W2 h' + b2)          -> column-sum over pairs -> Spart[b,i]
// block = 256 threads = 4 waves; wave w owns output cols [w*64, w*64+64).
// Weight fragments come from the fragment-major Wf layout (coalesced 1KB
// bursts). __launch_bounds__(256,3): total reg cap ~168 >= natural ~144
// (80 VGPR + 64 AGPR acc) -> no spill. Cap is on VGPR+AGPR combined;
// (256,4) spilled (~37MB scratch/dispatch), (256,5) was catastrophic.
// ---------------------------------------------------------------------------
__global__ __launch_bounds__(256, 3) void rn_main(
    const float* __restrict__ Lf, const float* __restrict__ Rf,
    const u16* __restrict__ Wf, const float* __restrict__ biasg,
    float* __restrict__ Spart) {
  __shared__ __align__(16) u16 hbuf[64 * 256];   // 32 KiB, reused per layer
  char* hb = (char*)hbuf;
  const int b = blockIdx.y;
  const int i = blockIdx.x;
  const int t = threadIdx.x;
  const int wave = t >> 6;
  const int lane = t & 63;
  const int g = lane >> 4;
  const int r = lane & 15;

  // ---- Phase 0: h[j][c] = relu(L[i][c] + R[j][c]), coalesced:
  // lane owns cols [lane*4, lane*4+4); L row loaded once; 16 coalesced R rows.
  {
    const float4 lv = *(const float4*)(Lf + ((size_t)b * 64 + i) * 256 + lane * 4);
    const float4* rbase = (const float4*)(Rf + (size_t)b * 64 * 256);
    #pragma unroll
    for (int q = 0; q < 16; ++q) {
      const int j = q * 4 + wave;
      const float4 rv = rbase[(size_t)j * 64 + lane];
      u16x4 pk;
      pk[0] = f2bf(fmaxf(lv.x + rv.x, 0.f));
      pk[1] = f2bf(fmaxf(lv.y + rv.y, 0.f));
      pk[2] = f2bf(fmaxf(lv.z + rv.z, 0.f));
      pk[3] = f2bf(fmaxf(lv.w + rv.w, 0.f));
      *(u16x4*)(hb + (j * 512 + ((lane * 8) ^ ((j & 7) << 4)))) = pk;
    }
  }
  __syncthreads();

  const int kl = g * 8;
  const f32x4 zero4 = {0.f, 0.f, 0.f, 0.f};
  f32x4 acc[4][4];

  // ---- Layer A: h -> acc (weights Wf layer 0)
  {
    #pragma unroll
    for (int mt = 0; mt < 4; ++mt)
      #pragma unroll
      for (int nt = 0; nt < 4; ++nt) acc[mt][nt] = zero4;
    const bf16x8* wb = (const bf16x8*)Wf;            // layer 0 fragments
    #pragma unroll
    for (int kk = 0; kk < 8; ++kk) {
      const int k = kk * 32 + kl;
      bf16x8 bfrag[4];
      #pragma unroll
      for (int nt = 0; nt < 4; ++nt)
        bfrag[nt] = wb[(kk * 16 + wave * 4 + nt) * 64 + lane];
      #pragma unroll
      for (int mt = 0; mt < 4; ++mt) {
        const int row = mt * 16 + r;
        const bf16x8 afrag =
            *(const bf16x8*)(hb + (row * 512 + ((k * 2) ^ ((row & 7) << 4))));
        #pragma unroll
        for (int nt = 0; nt < 4; ++nt)
          acc[mt][nt] = __builtin_amdgcn_mfma_f32_16x16x32_bf16(
              afrag, bfrag[nt], acc[mt][nt], 0, 0, 0);
      }
    }
  }
  __syncthreads();  // all reads of h done -> safe to overwrite

  // ---- write h' = relu(acc + b1) into the SAME buffer
  {
    #pragma unroll
    for (int nt = 0; nt < 4; ++nt) {
      const int col = wave * 64 + nt * 16 + r;
      const float bias = biasg[col];
      #pragma unroll
      for (int mt = 0; mt < 4; ++mt) {
        #pragma unroll
        for (int reg = 0; reg < 4; ++reg) {
          const int row = mt * 16 + g * 4 + reg;
          const float v = fmaxf(acc[mt][nt][reg] + bias, 0.f);
          *(u16*)(hb + (row * 512 + ((col * 2) ^ ((row & 7) << 4)))) = f2bf(v);
        }
      }
    }
  }
  __syncthreads();

  // ---- Layer B: h' -> relu -> column sums -> Spart (plain stores)
  {
    #pragma unroll
    for (int mt = 0; mt < 4; ++mt)
      #pragma unroll
      for (int nt = 0; nt < 4; ++nt) acc[mt][nt] = zero4;
    const bf16x8* wb = (const bf16x8*)(Wf + 65536);  // layer 1 fragments
    #pragma unroll
    for (int kk = 0; kk < 8; ++kk) {
      const int k = kk * 32 + kl;
      bf16x8 bfrag[4];
      #pragma unroll
      for (int nt = 0; nt < 4; ++nt)
        bfrag[nt] = wb[(kk * 16 + wave * 4 + nt) * 64 + lane];
      #pragma unroll
      for (int mt = 0; mt < 4; ++mt) {
        const int row = mt * 16 + r;
        const bf16x8 afrag =
            *(const bf16x8*)(hb + (row * 512 + ((k * 2) ^ ((row & 7) << 4))));
        #pragma unroll
        for (int nt = 0; nt < 4; ++nt)
          acc[mt][nt] = __builtin_amdgcn_mfma_f32_16x16x32_bf16(
              afrag, bfrag[nt], acc[mt][nt], 0, 0, 0);
      }
    }
    #pragma unroll
    for (int nt = 0; nt < 4; ++nt) {
      const int col = wave * 64 + nt * 16 + r;
      const float bias = biasg[256 + col];
      float cs = 0.f;
      #pragma unroll
      for (int mt = 0; mt < 4; ++mt)
        #pragma unroll
        for (int reg = 0; reg < 4; ++reg)
          cs += fmaxf(acc[mt][nt][reg] + bias, 0.f);
      cs += __shfl_xor(cs, 16, 64);
      cs += __shfl_xor(cs, 32, 64);
      if (lane < 16) Spart[(((size_t)b * 64 + i) * 256) + col] = cs;
    }
  }
}

// ---------------------------------------------------------------------------
// F head: per batch: reduce Spart over i (coalesced), then 2x(matvec+ReLU)
// with pre-folded COLUMN-MAJOR weights (coalesced loads), final 256->128.
// ---------------------------------------------------------------------------
__global__ __launch_bounds__(256) void head_kernel(
    const float* __restrict__ Spart, const float* __restrict__ fWt,
    const float* __restrict__ fbias, const float* __restrict__ foWt,
    const float* __restrict__ fob, float* __restrict__ out) {
  const int b = blockIdx.x;
  const int u = threadIdx.x;
  __shared__ __align__(16) float h[256];
  float s0 = 0.f;
  const float* sp = Spart + (size_t)b * 64 * 256 + u;
  #pragma unroll 8
  for (int ii = 0; ii < 64; ++ii) s0 += sp[ii * 256];
  h[u] = s0;
  __syncthreads();
  #pragma unroll
  for (int l = 0; l < 2; ++l) {
    const float* wc = fWt + (size_t)l * 65536 + u;  // column u, walk k
    float z = 0.f;
    #pragma unroll 8
    for (int k = 0; k < 256; ++k) z += wc[(size_t)k * 256] * h[k];
    z = fmaxf(z + fbias[l * 256 + u], 0.f);
    __syncthreads();
    h[u] = z;
    __syncthreads();
  }
  if (u < 128) {
    const float* wc = foWt + u;                     // column u, walk k
    float y = fob[u];
    #pragma unroll 8
    for (int k = 0; k < 256; ++k) y += wc[(size_t)k * 128] * h[k];
    out[(size_t)b * 128 + u] = y;
  }
}

extern "C" void kernel_launch(void* const* d_in, const int* in_sizes, int n_in,
                              void* d_out, int out_size, void* d_ws, size_t ws_size,
                              hipStream_t stream) {
  const float* x      = (const float*)d_in[0];
  const float* gW     = (const float*)d_in[1];
  const float* gb     = (const float*)d_in[2];
  const float* ggamma = (const float*)d_in[3];
  const float* gbeta  = (const float*)d_in[4];
  const float* gmean  = (const float*)d_in[5];
  const float* gvar   = (const float*)d_in[6];
  const float* fW     = (const float*)d_in[7];
  const float* fb     = (const float*)d_in[8];
  const float* fgamma = (const float*)d_in[9];
  const float* fbeta  = (const float*)d_in[10];
  const float* fmean  = (const float*)d_in[11];
  const float* fvar   = (const float*)d_in[12];
  const float* foW    = (const float*)d_in[13];
  const float* fob    = (const float*)d_in[14];

  // workspace layout
  u16* Wf = (u16*)d_ws;                    // 2*65536 bf16, fragment-major
  float* biasg = (float*)(Wf + 2 * 65536); // 512 f32
  float* fbias = biasg + 512;              // 512 f32
  float* fWt  = fbias + 512;               // 2*65536 f32, col-major folded
  float* foWt = fWt + 2 * 65536;           // 256*128 f32, col-major
  float* Lfp = foWt + 256 * 128;           // 32*64*256 f32
  float* Rfp = Lfp + 32 * 64 * 256;        // 32*64*256 f32
  float* Spart = Rfp + 32 * 64 * 256;      // 32*64*256 f32

  prep<<<dim3(328), 256, 0, stream>>>(x, gW, gb, ggamma, gbeta, gmean, gvar,
                                      fW, fb, fgamma, fbeta, fmean, fvar, foW,
                                      Wf, biasg, fWt, fbias, foWt, Lfp, Rfp);
  rn_main<<<dim3(64, 32), 256, 0, stream>>>(Lfp, Rfp, Wf, biasg, Spart);
  head_kernel<<<dim3(32), 256, 0, stream>>>(Spart, fWt, fbias, foWt, fob,
                                            (float*)d_out);
}

// Round 6
// 75.985 us; speedup vs baseline: 1.3648x; 1.3648x over previous
//
#include <hip/hip_runtime.h>
#include <hip/hip_bf16.h>

#define EPS 1e-5f

typedef unsigned short u16;
typedef __attribute__((ext_vector_type(8))) __bf16 bf16x8;
typedef __attribute__((ext_vector_type(4))) float f32x4;
typedef __attribute__((ext_vector_type(4))) unsigned short u16x4;

// round-to-nearest-even f32 -> bf16
__device__ __forceinline__ u16 f2bf(float f) {
  unsigned int u = __float_as_uint(f);
  u += 0x7fffu + ((u >> 16) & 1u);
  return (u16)(u >> 16);
}

// ---------------------------------------------------------------------------
// prep kernel (one launch, 328 independent blocks):
//   blocks   0..255 -> L/R projections (layer-0 fold), 8 objects each
//   blocks 256..287 -> fold BN into G layers 1,2, FRAGMENT-MAJOR bf16:
//       Wf[l][kk][cb][lane=g*16+r][e] = W_folded[u=cb*16+r][k=kk*32+g*8+e]
//   blocks 288..319 -> fold BN into F layers 0,1, K-BLOCKED col-major f32:
//       fWt[l][k>>2][u][k&3] = fW[l][u][k] * s[u]   (head lane loads float4)
//   blocks 320..327 -> final layer: foWt[k>>2][u][k&3] = foW[u][k]
// ---------------------------------------------------------------------------
__global__ __launch_bounds__(256) void prep(
    const float* __restrict__ x, const float* __restrict__ gW,
    const float* __restrict__ gb, const float* __restrict__ ggamma,
    const float* __restrict__ gbeta, const float* __restrict__ gmean,
    const float* __restrict__ gvar,
    const float* __restrict__ fW, const float* __restrict__ fb,
    const float* __restrict__ fgamma, const float* __restrict__ fbeta,
    const float* __restrict__ fmean, const float* __restrict__ fvar,
    const float* __restrict__ foW,
    u16* __restrict__ Wf, float* __restrict__ biasOut,
    float* __restrict__ fWt, float* __restrict__ fbias,
    float* __restrict__ foWt,
    float* __restrict__ Lf, float* __restrict__ Rf) {
  const int t = threadIdx.x;
  const int blk = blockIdx.x;

  if (blk >= 320) {
    // ---- foW k-blocked transpose: 8 blocks, 16 rows (u) each
    const int row = (blk - 320) * 16 + (t >> 4);
    const int c0 = (t & 15) * 16;
    const float* wrow = foW + (size_t)row * 256;
    #pragma unroll
    for (int c = 0; c < 16; ++c) {
      const int k = c0 + c;
      foWt[(((size_t)(k >> 2) * 128) + row) * 4 + (k & 3)] = wrow[k];
    }
    return;
  }
  if (blk >= 288) {
    // ---- F fold: 32 blocks, 16 rows (u) of one layer each
    const int idx = blk - 288;
    const int l = idx >> 4;
    const int row = (idx & 15) * 16 + (t >> 4);
    const int c0 = (t & 15) * 16;
    const int fi = l * 256 + row;
    const float s = fgamma[fi] * rsqrtf(fvar[fi] + EPS);
    if (c0 == 0) fbias[l * 256 + row] = (fb[fi] - fmean[fi]) * s + fbeta[fi];
    const float* wrow = fW + (size_t)fi * 256;
    #pragma unroll
    for (int c = 0; c < 16; ++c) {
      const int k = c0 + c;
      fWt[(((size_t)l * 64 + (k >> 2)) * 256 + row) * 4 + (k & 3)] =
          wrow[k] * s;
    }
    return;
  }
  if (blk >= 256) {
    // ---- G fold: 32 blocks, 16 rows (u) of one layer each
    const int idx = blk - 256;
    const int l = idx >> 4;                 // 0,1 -> g layer 1,2
    const int gl = l + 1;
    const int row = (idx & 15) * 16 + (t >> 4);
    const int c0 = (t & 15) * 16;
    const int gi = gl * 256 + row;
    const float s = ggamma[gi] * rsqrtf(gvar[gi] + EPS);
    if (c0 == 0) biasOut[l * 256 + row] = (gb[gi] - gmean[gi]) * s + gbeta[gi];
    const float* wrow = gW + (size_t)gi * 256;
    const int r = row & 15;
    const int cb = row >> 4;
    #pragma unroll
    for (int c = 0; c < 16; ++c) {
      const int k = c0 + c;
      const int kk = k >> 5;
      const int g = (k >> 3) & 3;
      const int e = k & 7;
      const size_t flat =
          (((((size_t)l * 8 + kk) * 16 + cb) * 64) + g * 16 + r) * 8 + e;
      Wf[flat] = f2bf(wrow[k] * s);
    }
    return;
  }
  // ---- L/R part: 256 blocks = 32 batches x 8 chunks of 8 objects
  const int b = blk >> 3;
  const int chunk = blk & 7;
  __shared__ __align__(16) float xs[8][128];
  {
    const float4* src = (const float4*)(x + ((size_t)b * 64 + chunk * 8) * 128);
    float4* dst = (float4*)(&xs[0][0]);
    if (t < 256) dst[t] = src[t];
  }
  __syncthreads();
  const int u = t;
  float accL[8], accR[8];
  #pragma unroll
  for (int nn = 0; nn < 8; ++nn) { accL[nn] = 0.f; accR[nn] = 0.f; }
  const float4* wl = (const float4*)(gW + (size_t)u * 256);
  const float4* wr = (const float4*)(gW + (size_t)u * 256 + 128);
  for (int d4 = 0; d4 < 32; ++d4) {
    const float4 a = wl[d4];
    const float4 c = wr[d4];
    #pragma unroll
    for (int nn = 0; nn < 8; ++nn) {
      const float4 xv = *((const float4*)&xs[nn][d4 * 4]);
      accL[nn] += a.x * xv.x + a.y * xv.y + a.z * xv.z + a.w * xv.w;
      accR[nn] += c.x * xv.x + c.y * xv.y + c.z * xv.z + c.w * xv.w;
    }
  }
  const float s = ggamma[u] * rsqrtf(gvar[u] + EPS);
  const float lb = (gb[u] - gmean[u]) * s + gbeta[u];
  const int n0 = chunk * 8;
  #pragma unroll
  for (int nn = 0; nn < 8; ++nn) {
    Lf[((size_t)b * 64 + n0 + nn) * 256 + u] = accL[nn] * s + lb;
    Rf[((size_t)b * 64 + n0 + nn) * 256 + u] = accR[nn] * s;
  }
}

// ---------------------------------------------------------------------------
// Main fused kernel: per (ig, b): TWO i-values (i0=2ig, i0+1), 128 pair-rows.
//   h  = relu(L_i + R_j)   -> LDS bf16 (XOR-swizzled), 128 rows, 64 KiB
//   h' = relu(W1 h + b1)   -> same LDS buffer (acc in regs across barrier)
//   out = relu(W2 h' + b2) -> per-i column sums -> Spart[b,ig]
// Rationale: rn_main is L2-BW-bound on weight refetch (each block reads
// 256 KB of weights from L2; round-5: 2048 blocks * 256KB = 512 MB ~= the
// 51 us). Doubling rows per block halves weight traffic per FLOP.
// block = 256 threads = 4 waves; wave w owns output cols [w*64, w*64+64),
// mt=8 row-fragments (acc[8][4] = 128 AGPR). __launch_bounds__(256,2):
// cap 256 total regs (VGPR+AGPR unified) >= natural ~220 -> no spill.
// LDS 64 KiB -> 2 blocks/CU.
// ---------------------------------------------------------------------------
__global__ __launch_bounds__(256, 2) void rn_main(
    const float* __restrict__ Lf, const float* __restrict__ Rf,
    const u16* __restrict__ Wf, const float* __restrict__ biasg,
    float* __restrict__ Spart) {
  __shared__ __align__(16) u16 hbuf[128 * 256];   // 64 KiB, reused per layer
  char* hb = (char*)hbuf;
  const int b = blockIdx.y;
  const int ig = blockIdx.x;             // i-group of 2
  const int t = threadIdx.x;
  const int wave = t >> 6;
  const int lane = t & 63;
  const int g = lane >> 4;
  const int r = lane & 15;

  // ---- Phase 0: rows p = it*64+j; h[p][c] = relu(L[2ig+it][c] + R[j][c])
  // lane owns cols [lane*4, lane*4+4); p = q*4 + wave (q<16 -> it=0).
  {
    const float4 lv0 =
        *(const float4*)(Lf + ((size_t)b * 64 + ig * 2) * 256 + lane * 4);
    const float4 lv1 =
        *(const float4*)(Lf + ((size_t)b * 64 + ig * 2 + 1) * 256 + lane * 4);
    const float4* rbase = (const float4*)(Rf + (size_t)b * 64 * 256);
    #pragma unroll
    for (int q = 0; q < 32; ++q) {
      const int p = q * 4 + wave;
      const int j = p & 63;
      const float4 rv = rbase[(size_t)j * 64 + lane];
      const float4 lv = (q < 16) ? lv0 : lv1;
      u16x4 pk;
      pk[0] = f2bf(fmaxf(lv.x + rv.x, 0.f));
      pk[1] = f2bf(fmaxf(lv.y + rv.y, 0.f));
      pk[2] = f2bf(fmaxf(lv.z + rv.z, 0.f));
      pk[3] = f2bf(fmaxf(lv.w + rv.w, 0.f));
      *(u16x4*)(hb + (p * 512 + ((lane * 8) ^ ((p & 7) << 4)))) = pk;
    }
  }
  __syncthreads();

  const f32x4 zero4 = {0.f, 0.f, 0.f, 0.f};
  f32x4 acc[8][4];

  // ---- Layer A: h -> acc (weights Wf layer 0)
  {
    #pragma unroll
    for (int mt = 0; mt < 8; ++mt)
      #pragma unroll
      for (int nt = 0; nt < 4; ++nt) acc[mt][nt] = zero4;
    const bf16x8* wb = (const bf16x8*)Wf;            // layer 0 fragments
    #pragma unroll
    for (int kk = 0; kk < 8; ++kk) {
      bf16x8 bfrag[4];
      #pragma unroll
      for (int nt = 0; nt < 4; ++nt)
        bfrag[nt] = wb[(kk * 16 + wave * 4 + nt) * 64 + lane];
      #pragma unroll
      for (int mt = 0; mt < 8; ++mt) {
        const int row = mt * 16 + r;
        const bf16x8 afrag = *(const bf16x8*)(
            hb + (row * 512 + ((kk * 64 + g * 16) ^ ((r & 7) << 4))));
        #pragma unroll
        for (int nt = 0; nt < 4; ++nt)
          acc[mt][nt] = __builtin_amdgcn_mfma_f32_16x16x32_bf16(
              afrag, bfrag[nt], acc[mt][nt], 0, 0, 0);
      }
    }
  }
  __syncthreads();  // all reads of h done -> safe to overwrite

  // ---- write h' = relu(acc + b1) into the SAME buffer
  {
    #pragma unroll
    for (int nt = 0; nt < 4; ++nt) {
      const int col = wave * 64 + nt * 16 + r;
      const float bias = biasg[col];
      #pragma unroll
      for (int mt = 0; mt < 8; ++mt) {
        #pragma unroll
        for (int reg = 0; reg < 4; ++reg) {
          const int row = mt * 16 + g * 4 + reg;
          const float v = fmaxf(acc[mt][nt][reg] + bias, 0.f);
          *(u16*)(hb + (row * 512 + ((col * 2) ^ ((row & 7) << 4)))) = f2bf(v);
        }
      }
    }
  }
  __syncthreads();

  // ---- Layer B: h' -> relu -> per-i column sums -> Spart (plain stores)
  {
    #pragma unroll
    for (int mt = 0; mt < 8; ++mt)
      #pragma unroll
      for (int nt = 0; nt < 4; ++nt) acc[mt][nt] = zero4;
    const bf16x8* wb = (const bf16x8*)(Wf + 65536);  // layer 1 fragments
    #pragma unroll
    for (int kk = 0; kk < 8; ++kk) {
      bf16x8 bfrag[4];
      #pragma unroll
      for (int nt = 0; nt < 4; ++nt)
        bfrag[nt] = wb[(kk * 16 + wave * 4 + nt) * 64 + lane];
      #pragma unroll
      for (int mt = 0; mt < 8; ++mt) {
        const int row = mt * 16 + r;
        const bf16x8 afrag = *(const bf16x8*)(
            hb + (row * 512 + ((kk * 64 + g * 16) ^ ((r & 7) << 4))));
        #pragma unroll
        for (int nt = 0; nt < 4; ++nt)
          acc[mt][nt] = __builtin_amdgcn_mfma_f32_16x16x32_bf16(
              afrag, bfrag[nt], acc[mt][nt], 0, 0, 0);
      }
    }
    // rows 0..63 belong to i=2ig, rows 64..127 to i=2ig+1; sum each half.
    #pragma unroll
    for (int nt = 0; nt < 4; ++nt) {
      const int col = wave * 64 + nt * 16 + r;
      const float bias = biasg[256 + col];
      float cs0 = 0.f, cs1 = 0.f;
      #pragma unroll
      for (int mt = 0; mt < 4; ++mt)
        #pragma unroll
        for (int reg = 0; reg < 4; ++reg)
          cs0 += fmaxf(acc[mt][nt][reg] + bias, 0.f);
      #pragma unroll
      for (int mt = 4; mt < 8; ++mt)
        #pragma unroll
        for (int reg = 0; reg < 4; ++reg)
          cs1 += fmaxf(acc[mt][nt][reg] + bias, 0.f);
      float cs = cs0 + cs1;  // G-sum is over ALL pairs; both i contribute
      cs += __shfl_xor(cs, 16, 64);
      cs += __shfl_xor(cs, 32, 64);
      if (lane < 16) Spart[(((size_t)b * 32 + ig) * 256) + col] = cs;
    }
  }
}

// ---------------------------------------------------------------------------
// F head: per batch: reduce Spart over 32 i-groups (coalesced), then
// 2x(matvec+ReLU) + final 256->128, with K-BLOCKED col-major weights so each
// lane loads float4 along k (coalesced 4 KB per wave-instruction).
// ---------------------------------------------------------------------------
__global__ __launch_bounds__(256) void head_kernel(
    const float* __restrict__ Spart, const float* __restrict__ fWt,
    const float* __restrict__ fbias, const float* __restrict__ foWt,
    const float* __restrict__ fob, float* __restrict__ out) {
  const int b = blockIdx.x;
  const int u = threadIdx.x;
  __shared__ __align__(16) float h[256];
  float s0 = 0.f;
  const float* sp = Spart + (size_t)b * 32 * 256 + u;
  #pragma unroll 8
  for (int ii = 0; ii < 32; ++ii) s0 += sp[ii * 256];
  h[u] = s0;
  __syncthreads();
  #pragma unroll
  for (int l = 0; l < 2; ++l) {
    const float4* wc = (const float4*)fWt + ((size_t)l * 64) * 256 + u;
    float z = 0.f;
    #pragma unroll 8
    for (int k4 = 0; k4 < 64; ++k4) {
      const float4 wv = wc[(size_t)k4 * 256];
      const float4 hv = *((const float4*)&h[k4 * 4]);
      z += wv.x * hv.x + wv.y * hv.y + wv.z * hv.z + wv.w * hv.w;
    }
    z = fmaxf(z + fbias[l * 256 + u], 0.f);
    __syncthreads();
    h[u] = z;
    __syncthreads();
  }
  if (u < 128) {
    const float4* wc = (const float4*)foWt + u;
    float y = fob[u];
    #pragma unroll 8
    for (int k4 = 0; k4 < 64; ++k4) {
      const float4 wv = wc[(size_t)k4 * 128];
      const float4 hv = *((const float4*)&h[k4 * 4]);
      y += wv.x * hv.x + wv.y * hv.y + wv.z * hv.z + wv.w * hv.w;
    }
    out[(size_t)b * 128 + u] = y;
  }
}

extern "C" void kernel_launch(void* const* d_in, const int* in_sizes, int n_in,
                              void* d_out, int out_size, void* d_ws, size_t ws_size,
                              hipStream_t stream) {
  const float* x      = (const float*)d_in[0];
  const float* gW     = (const float*)d_in[1];
  const float* gb     = (const float*)d_in[2];
  const float* ggamma = (const float*)d_in[3];
  const float* gbeta  = (const float*)d_in[4];
  const float* gmean  = (const float*)d_in[5];
  const float* gvar   = (const float*)d_in[6];
  const float* fW     = (const float*)d_in[7];
  const float* fb     = (const float*)d_in[8];
  const float* fgamma = (const float*)d_in[9];
  const float* fbeta  = (const float*)d_in[10];
  const float* fmean  = (const float*)d_in[11];
  const float* fvar   = (const float*)d_in[12];
  const float* foW    = (const float*)d_in[13];
  const float* fob    = (const float*)d_in[14];

  // workspace layout
  u16* Wf = (u16*)d_ws;                    // 2*65536 bf16, fragment-major
  float* biasg = (float*)(Wf + 2 * 65536); // 512 f32
  float* fbias = biasg + 512;              // 512 f32
  float* fWt  = fbias + 512;               // 2*65536 f32, k-blocked col-major
  float* foWt = fWt + 2 * 65536;           // 256*128 f32, k-blocked col-major
  float* Lfp = foWt + 256 * 128;           // 32*64*256 f32
  float* Rfp = Lfp + 32 * 64 * 256;        // 32*64*256 f32
  float* Spart = Rfp + 32 * 64 * 256;      // 32*32*256 f32

  prep<<<dim3(328), 256, 0, stream>>>(x, gW, gb, ggamma, gbeta, gmean, gvar,
                                      fW, fb, fgamma, fbeta, fmean, fvar, foW,
                                      Wf, biasg, fWt, fbias, foWt, Lfp, Rfp);
  rn_main<<<dim3(32, 32), 256, 0, stream>>>(Lfp, Rfp, Wf, biasg, Spart);
  head_kernel<<<dim3(32), 256, 0, stream>>>(Spart, fWt, fbias, foWt, fob,
                                            (float*)d_out);
}